// Round 1
// baseline (1159.714 us; speedup 1.0000x reference)
//
#include <hip/hip_runtime.h>
#include <math.h>

#define NTOT   131072
#define NPG    256
#define BGR    512
#define HID    128
#define EDG    2097152
#define CAP    48          // max in-degree ~40 for Binom(4096,1/256) over 131072 nodes
#define KTOP   60
#define TLDIM  385

// ---------------- graph build ----------------
__global__ __launch_bounds__(256) void k_init(int* __restrict__ cnt) {
    int i = blockIdx.x * 256 + threadIdx.x;
    if (i < NTOT) cnt[i] = 0;
}

__global__ __launch_bounds__(256) void k_build(const int* __restrict__ ei,
                                               int* __restrict__ cnt,
                                               int* __restrict__ adjs) {
    int e = blockIdx.x * 256 + threadIdx.x;
    if (e >= EDG) return;
    int dst = ei[EDG + e];                 // edge_index[1][e]
    int pos = atomicAdd(&cnt[dst], 1);
    if (pos < CAP) adjs[(size_t)dst * CAP + pos] = e;
}

// sort each node's edge ids ascending (deterministic sum order), compute deg
__global__ __launch_bounds__(256) void k_sortdeg(const float* __restrict__ ew,
                                                 int* __restrict__ adjs,
                                                 int* __restrict__ cnt,
                                                 float* __restrict__ deg) {
    int n = blockIdx.x * 256 + threadIdx.x;
    if (n >= NTOT) return;
    int m = cnt[n];
    if (m > CAP) { m = CAP; cnt[n] = CAP; }
    int* a = adjs + (size_t)n * CAP;
    for (int i = 1; i < m; i++) {
        int key = a[i]; int j = i - 1;
        while (j >= 0 && a[j] > key) { a[j + 1] = a[j]; j--; }
        a[j + 1] = key;
    }
    float s = 0.f;
    for (int i = 0; i < m; i++) s += ew[a[i]];
    deg[n] = s + 1.0f;                      // self-loop weight appended last (ref order)
}

__global__ __launch_bounds__(256) void k_dinv(float* __restrict__ deg) {
    int n = blockIdx.x * 256 + threadIdx.x;
    if (n < NTOT) deg[n] = 1.0f / sqrtf(deg[n]);   // deg >= 1 always
}

// rewrite adjacency: edge id -> (src, norm)
__global__ __launch_bounds__(256) void k_fin(const int* __restrict__ ei,
                                             const float* __restrict__ ew,
                                             const float* __restrict__ dinv,
                                             const int* __restrict__ cnt,
                                             int* __restrict__ adjs,
                                             float* __restrict__ adjw) {
    int n = blockIdx.x * 256 + threadIdx.x;
    if (n >= NTOT) return;
    int m = cnt[n];
    float dn = dinv[n];
    for (int i = 0; i < m; i++) {
        int e = adjs[(size_t)n * CAP + i];
        int s = ei[e];                       // edge_index[0][e]
        adjs[(size_t)n * CAP + i] = s;
        adjw[(size_t)n * CAP + i] = dinv[s] * ew[e] * dn;  // (dinv[src]*ew)*dinv[dst]
    }
}

// ---------------- embedding gather ----------------
__global__ __launch_bounds__(256) void k_embed(const float* __restrict__ zt,
                                               const int* __restrict__ z,
                                               float* __restrict__ X) {
    int i = blockIdx.x * 256 + threadIdx.x;   // over NTOT*32 float4s
    int n = i >> 5, q = i & 31;
    int zi = z[n];
    ((float4*)X)[(size_t)n * 32 + q] = ((const float4*)zt)[(size_t)zi * 32 + q];
}

// ---------------- fused GCN layer: agg(x) then @W + b, tanh ----------------
__global__ __launch_bounds__(256) void k_layer(const float* __restrict__ Xin,
                                               float* __restrict__ Xout,
                                               const int* __restrict__ cnt,
                                               const int* __restrict__ adjs,
                                               const float* __restrict__ adjw,
                                               const float* __restrict__ dinv,
                                               const float* __restrict__ W,
                                               const float* __restrict__ bias) {
    __shared__ float agg[64][129];                 // stride 129 -> conflict-free reads
    __shared__ __align__(16) float WL[32 * 128];   // one 32-k chunk of W
    int t = threadIdx.x;
    int base = blockIdx.x * 64;

    // ---- step 1: aggregate 64 rows (4 threads per node, 32 channels each) ----
    {
        int local = t >> 2;
        int node  = base + local;
        int c4    = (t & 3) * 8;                   // float4 index within row
        float4 acc[8];
#pragma unroll
        for (int q = 0; q < 8; q++) acc[q] = make_float4(0.f, 0.f, 0.f, 0.f);
        int m = cnt[node];
        if (m > CAP) m = CAP;
        const int*   as = adjs + (size_t)node * CAP;
        const float* aw = adjw + (size_t)node * CAP;
        for (int j = 0; j < m; j++) {
            int s = as[j];
            float wgt = aw[j];
            const float4* r = ((const float4*)Xin) + (size_t)s * 32 + c4;
#pragma unroll
            for (int q = 0; q < 8; q++) {
                float4 v = r[q];
                acc[q].x += wgt * v.x; acc[q].y += wgt * v.y;
                acc[q].z += wgt * v.z; acc[q].w += wgt * v.w;
            }
        }
        float dv = dinv[node];
        float ws = dv * dv;                        // self-loop norm, added last (ref order)
        const float4* r = ((const float4*)Xin) + (size_t)node * 32 + c4;
#pragma unroll
        for (int q = 0; q < 8; q++) {
            float4 v = r[q];
            acc[q].x += ws * v.x; acc[q].y += ws * v.y;
            acc[q].z += ws * v.z; acc[q].w += ws * v.w;
        }
#pragma unroll
        for (int q = 0; q < 8; q++) {
            int c = (c4 + q) * 4;
            agg[local][c + 0] = acc[q].x; agg[local][c + 1] = acc[q].y;
            agg[local][c + 2] = acc[q].z; agg[local][c + 3] = acc[q].w;
        }
    }

    // ---- step 2: 64x128 (LDS) @ 128x128 (W), each thread 8 rows x 4 cols ----
    int rg = t & 7, cg = t >> 3;                   // rows rg*8..rg*8+7, cols cg*4..+3
    float a2[8][4];
#pragma unroll
    for (int i = 0; i < 8; i++)
#pragma unroll
        for (int j = 0; j < 4; j++) a2[i][j] = 0.f;

    for (int kc = 0; kc < 4; kc++) {
        __syncthreads();                            // step1 done / prev chunk consumed
        const float4* Wg = (const float4*)(W + kc * 32 * HID);
#pragma unroll
        for (int i = 0; i < 4; i++) ((float4*)WL)[t + 256 * i] = Wg[t + 256 * i];
        __syncthreads();
#pragma unroll
        for (int kk = 0; kk < 32; kk++) {
            float4 wv = *((float4*)&WL[kk * 128 + cg * 4]);
            float av[8];
#pragma unroll
            for (int i = 0; i < 8; i++) av[i] = agg[rg * 8 + i][kc * 32 + kk];
#pragma unroll
            for (int i = 0; i < 8; i++) {
                a2[i][0] += av[i] * wv.x; a2[i][1] += av[i] * wv.y;
                a2[i][2] += av[i] * wv.z; a2[i][3] += av[i] * wv.w;
            }
        }
    }

    float4 bv = *((const float4*)&bias[cg * 4]);
#pragma unroll
    for (int i = 0; i < 8; i++) {
        int row = base + rg * 8 + i;
        float4 o;
        o.x = tanhf(a2[i][0] + bv.x); o.y = tanhf(a2[i][1] + bv.y);
        o.z = tanhf(a2[i][2] + bv.z); o.w = tanhf(a2[i][3] + bv.w);
        *((float4*)&Xout[(size_t)row * HID + cg * 4]) = o;
    }
}

// ---------------- layer 3 (128 -> 1): dot then scalar aggregation ----------------
__global__ __launch_bounds__(256) void k_dot3(const float* __restrict__ X2,
                                              const float* __restrict__ W3,
                                              float* __restrict__ t3) {
    int t = threadIdx.x;
    int n = blockIdx.x * 64 + (t >> 2);
    int part = t & 3;
    const float4* r = ((const float4*)X2) + (size_t)n * 32 + part * 8;
    const float4* w = ((const float4*)W3) + part * 8;
    float s = 0.f;
#pragma unroll
    for (int q = 0; q < 8; q++) {
        float4 v = r[q]; float4 ww = w[q];
        s += v.x * ww.x + v.y * ww.y + v.z * ww.z + v.w * ww.w;
    }
    s += __shfl_down(s, 2, 4);
    s += __shfl_down(s, 1, 4);
    if (part == 0) t3[n] = s;
}

__global__ __launch_bounds__(256) void k_agg3(const float* __restrict__ t3,
                                              const int* __restrict__ cnt,
                                              const int* __restrict__ adjs,
                                              const float* __restrict__ adjw,
                                              const float* __restrict__ dinv,
                                              const float* __restrict__ b3,
                                              float* __restrict__ key) {
    int n = blockIdx.x * 256 + threadIdx.x;
    if (n >= NTOT) return;
    int m = cnt[n];
    if (m > CAP) m = CAP;
    float s = 0.f;
    for (int j = 0; j < m; j++)
        s += adjw[(size_t)n * CAP + j] * t3[adjs[(size_t)n * CAP + j]];
    float dv = dinv[n];
    s += dv * dv * t3[n];
    key[n] = tanhf(s + b3[0]);
}

// ---------------- stable top-60 per graph (exact argsort semantics) ----------------
__global__ __launch_bounds__(256) void k_select(const float* __restrict__ key,
                                                int* __restrict__ sel) {
    __shared__ float ks[NPG];
    int g = blockIdx.x, t = threadIdx.x;
    ks[t] = key[g * NPG + t];
    __syncthreads();
    float ki = ks[t];
    int rank = 0;
    for (int j = 0; j < NPG; j++) {
        float kj = ks[j];
        rank += (kj > ki) || (kj == ki && j < t);   // stable descending
    }
    if (rank < KTOP) sel[g * KTOP + rank] = g * NPG + t;
}

// ---------------- conv/MLP head: one block per graph ----------------
__global__ __launch_bounds__(256) void k_head(const float* __restrict__ X0,
                                              const float* __restrict__ X1,
                                              const float* __restrict__ X2,
                                              const float* __restrict__ key,
                                              const int* __restrict__ sel,
                                              const float* __restrict__ c1w,
                                              const float* __restrict__ c1b,
                                              const float* __restrict__ c2w,
                                              const float* __restrict__ c2b,
                                              const float* __restrict__ l1w,
                                              const float* __restrict__ l1b,
                                              const float* __restrict__ l2w,
                                              const float* __restrict__ l2b,
                                              float* __restrict__ out) {
    __shared__ __align__(16) float pch[KTOP * 132];   // pooled chunk, stride 132
    __shared__ __align__(16) float w1s[16 * 132];
    __shared__ int   seln[KTOP];
    __shared__ float selk[KTOP];
    __shared__ float c1s[16 * KTOP];
    __shared__ float mps[16 * 30];
    __shared__ float w2s[32 * 80];
    __shared__ float yb[832];
    __shared__ float l1p[256];
    __shared__ float l1v[128];

    int g = blockIdx.x, t = threadIdx.x;
    if (t < KTOP) {
        int nd = sel[g * KTOP + t];
        seln[t] = nd;
        selk[t] = key[nd];
    }

    float acc1[4] = {0.f, 0.f, 0.f, 0.f};
    for (int tc = 0; tc < 3; tc++) {
        const float* Xsrc = (tc == 0) ? X0 : ((tc == 1) ? X1 : X2);
        __syncthreads();
        // stage pooled chunk: 60 rows x 128 ch (float4)
        for (int i = t; i < KTOP * 32; i += 256) {
            int k = i >> 5, q = i & 31;
            int nd = seln[k];
            *((float4*)&pch[k * 132 + q * 4]) = ((const float4*)Xsrc)[(size_t)nd * 32 + q];
        }
        // stage conv1 weight chunk
        for (int i = t; i < 16 * 128; i += 256) {
            int ch = i >> 7, tt = i & 127;
            w1s[ch * 132 + tt] = c1w[ch * TLDIM + tc * 128 + tt];
        }
        __syncthreads();
#pragma unroll
        for (int it = 0; it < 4; it++) {
            int e = it * 256 + t;
            if (e < 960) {                        // e = k*16 + ch
                int k = e >> 4, ch = e & 15;
                const float* pr = &pch[k * 132];
                const float* wr = &w1s[ch * 132];
                float s = 0.f;
#pragma unroll
                for (int q = 0; q < 32; q++) {
                    float4 pv = *((float4*)&pr[q * 4]);
                    float4 wv = *((float4*)&wr[q * 4]);
                    s += pv.x * wv.x + pv.y * wv.y + pv.z * wv.z + pv.w * wv.w;
                }
                acc1[it] += s;
            }
        }
    }
    __syncthreads();
    // conv1 epilogue: + key channel (t=384) + bias, relu
#pragma unroll
    for (int it = 0; it < 4; it++) {
        int e = it * 256 + t;
        if (e < 960) {
            int k = e >> 4, ch = e & 15;
            float v = acc1[it] + selk[k] * c1w[ch * TLDIM + 384] + c1b[ch];
            c1s[ch * KTOP + k] = fmaxf(v, 0.f);
        }
    }
    for (int i = t; i < 2560; i += 256) w2s[i] = c2w[i];
    __syncthreads();
    // maxpool(2,2) over k
    for (int i = t; i < 480; i += 256) {
        int ch = i / 30, p = i - ch * 30;
        mps[ch * 30 + p] = fmaxf(c1s[ch * KTOP + 2 * p], c1s[ch * KTOP + 2 * p + 1]);
    }
    __syncthreads();
    // conv2: 32 oc x 26 pos, 16ic x 5 taps
    for (int e = t; e < 832; e += 256) {
        int oc = e / 26, q = e - oc * 26;
        float s = 0.f;
#pragma unroll
        for (int ic = 0; ic < 16; ic++) {
            const float* mr = &mps[ic * 30 + q];
            const float* wr = &w2s[oc * 80 + ic * 5];
#pragma unroll
            for (int j = 0; j < 5; j++) s += mr[j] * wr[j];
        }
        yb[e] = fmaxf(s + c2b[oc], 0.f);
    }
    __syncthreads();
    // lin1: 832 -> 128, split d-range over 2 half-warps of threads
    {
        int u = t & 127, h = t >> 7;
        float s = 0.f;
        for (int d = h * 416; d < h * 416 + 416; d++) s += yb[d] * l1w[d * 128 + u];
        l1p[t] = s;
    }
    __syncthreads();
    if (t < 128) {
        float v = fmaxf(l1p[t] + l1p[t + 128] + l1b[t], 0.f);
        l1v[t] = v * l2w[t];
    }
    __syncthreads();
    if (t < 64) {
        float v = l1v[t] + l1v[t + 64];
        v += __shfl_down(v, 32);
        v += __shfl_down(v, 16);
        v += __shfl_down(v, 8);
        v += __shfl_down(v, 4);
        v += __shfl_down(v, 2);
        v += __shfl_down(v, 1);
        if (t == 0) out[g] = v + l2b[0];
    }
}

extern "C" void kernel_launch(void* const* d_in, const int* in_sizes, int n_in,
                              void* d_out, int out_size, void* d_ws, size_t ws_size,
                              hipStream_t stream) {
    (void)in_sizes; (void)n_in; (void)out_size; (void)ws_size;
    const float* zt  = (const float*)d_in[0];
    const float* W0  = (const float*)d_in[1];
    const float* b0  = (const float*)d_in[2];
    const float* W1  = (const float*)d_in[3];
    const float* b1  = (const float*)d_in[4];
    const float* W2  = (const float*)d_in[5];
    const float* b2  = (const float*)d_in[6];
    const float* W3  = (const float*)d_in[7];
    const float* b3  = (const float*)d_in[8];
    const float* c1w = (const float*)d_in[9];
    const float* c1b = (const float*)d_in[10];
    const float* c2w = (const float*)d_in[11];
    const float* c2b = (const float*)d_in[12];
    const float* l1w = (const float*)d_in[13];
    const float* l1b = (const float*)d_in[14];
    const float* l2w = (const float*)d_in[15];
    const float* l2b = (const float*)d_in[16];
    const float* ew  = (const float*)d_in[17];
    const int*   z   = (const int*)d_in[18];
    const int*   ei  = (const int*)d_in[19];
    float* out = (float*)d_out;

    char* wsp = (char*)d_ws;
    size_t off = 0;
    auto alloc = [&](size_t bytes) -> void* {
        void* p = wsp + off;
        off += (bytes + 255) & ~(size_t)255;
        return p;
    };
    float* deg  = (float*)alloc((size_t)NTOT * 4);            // becomes dinv after k_dinv
    int*   cnt  = (int*)  alloc((size_t)NTOT * 4);
    int*   adjs = (int*)  alloc((size_t)NTOT * CAP * 4);
    float* adjw = (float*)alloc((size_t)NTOT * CAP * 4);
    float* XA   = (float*)alloc((size_t)NTOT * HID * 4);      // emb, later X1
    float* XB   = (float*)alloc((size_t)NTOT * HID * 4);      // X0
    float* XC   = (float*)alloc((size_t)NTOT * HID * 4);      // X2
    float* t3   = (float*)alloc((size_t)NTOT * 4);
    float* keyb = (float*)alloc((size_t)NTOT * 4);
    int*   sel  = (int*)  alloc((size_t)BGR * KTOP * 4);

    dim3 b256(256);
    k_init   <<<NTOT / 256,      b256, 0, stream>>>(cnt);
    k_build  <<<EDG / 256,       b256, 0, stream>>>(ei, cnt, adjs);
    k_sortdeg<<<NTOT / 256,      b256, 0, stream>>>(ew, adjs, cnt, deg);
    k_dinv   <<<NTOT / 256,      b256, 0, stream>>>(deg);
    k_fin    <<<NTOT / 256,      b256, 0, stream>>>(ei, ew, deg, cnt, adjs, adjw);
    k_embed  <<<NTOT * 32 / 256, b256, 0, stream>>>(zt, z, XA);
    k_layer  <<<NTOT / 64,       b256, 0, stream>>>(XA, XB, cnt, adjs, adjw, deg, W0, b0); // X0
    k_layer  <<<NTOT / 64,       b256, 0, stream>>>(XB, XA, cnt, adjs, adjw, deg, W1, b1); // X1
    k_layer  <<<NTOT / 64,       b256, 0, stream>>>(XA, XC, cnt, adjs, adjw, deg, W2, b2); // X2
    k_dot3   <<<NTOT / 64,       b256, 0, stream>>>(XC, W3, t3);
    k_agg3   <<<NTOT / 256,      b256, 0, stream>>>(t3, cnt, adjs, adjw, deg, b3, keyb);
    k_select <<<BGR,             b256, 0, stream>>>(keyb, sel);
    k_head   <<<BGR,             b256, 0, stream>>>(XB, XA, XC, keyb, sel,
                                                    c1w, c1b, c2w, c2b,
                                                    l1w, l1b, l2w, l2b, out);
}